// Round 4
// baseline (206.509 us; speedup 1.0000x reference)
//
#include <hip/hip_runtime.h>
#include <hip/hip_bf16.h>

#define CIN 256
#define NV 4096
#define NHEAD 8
#define HD 32
#define NSPLIT 2
#define KSPAN (NV / NSPLIT)

typedef __attribute__((ext_vector_type(8))) short short8;
typedef __attribute__((ext_vector_type(4))) float f32x4;

static __device__ __forceinline__ unsigned short f2bf(float f) {
    union { float f; unsigned u; } v; v.f = f;
    unsigned r = v.u + 0x7fffu + ((v.u >> 16) & 1u);  // RNE
    return (unsigned short)(r >> 16);
}

// ---------------------------------------------------------------------------
// Kernel 1: QKV projection + RoPE, emitting bf16 in MFMA-friendly layouts:
//   Q,K -> [h][n][c]  (per-query 32-channel rows; 4-channel-packed b64 stores)
//   V   -> [c][n]     (key-contiguous rows)
// grid (NV/64, CIN/64, 3), block 256.  blockIdx.z: 0=Q,1=K,2=V
// ---------------------------------------------------------------------------
__global__ __launch_bounds__(256) void qkv_proj(
    const float* __restrict__ x,
    const float* __restrict__ wq, const float* __restrict__ bq,
    const float* __restrict__ wk, const float* __restrict__ bk,
    const float* __restrict__ wv, const float* __restrict__ bv,
    unsigned short* __restrict__ Qbf, unsigned short* __restrict__ Kbf,
    unsigned short* __restrict__ Vbf)
{
    const int which = blockIdx.z;
    const float* W = (which == 0) ? wq : (which == 1) ? wk : wv;
    const float* B = (which == 0) ? bq : (which == 1) ? bk : bv;
    const float* X = x + (which == 0 ? 0 : (size_t)CIN * NV);

    const int n0 = blockIdx.x * 64;
    const int m0 = blockIdx.y * 64;
    const int t = threadIdx.x;
    const int tx = t & 15, ty = t >> 4;

    __shared__ float Wts[16][64];
    __shared__ float Xs[16][64];

    float acc[4][4] = {};

    for (int k0 = 0; k0 < CIN; k0 += 16) {
        {
            int row = t >> 2, c4 = (t & 3) * 4;
            float4 w4 = *(const float4*)&W[(size_t)(m0 + row) * CIN + k0 + c4];
            Wts[c4 + 0][row] = w4.x;
            Wts[c4 + 1][row] = w4.y;
            Wts[c4 + 2][row] = w4.z;
            Wts[c4 + 3][row] = w4.w;
        }
        {
            int xr = t >> 4, xc = (t & 15) * 4;
            *(float4*)&Xs[xr][xc] =
                *(const float4*)&X[(size_t)(k0 + xr) * NV + n0 + xc];
        }
        __syncthreads();
#pragma unroll
        for (int kk = 0; kk < 16; ++kk) {
            float a[4], b[4];
            *(float4*)a = *(const float4*)&Wts[kk][ty * 4];
            *(float4*)b = *(const float4*)&Xs[kk][tx * 4];
#pragma unroll
            for (int i = 0; i < 4; ++i)
#pragma unroll
                for (int j = 0; j < 4; ++j) acc[i][j] += a[i] * b[j];
        }
        __syncthreads();
    }

    if (which == 2) {
#pragma unroll
        for (int i = 0; i < 4; ++i) {
            const int m = m0 + ty * 4 + i;
            const float bias = B[m];
            unsigned short pk[4];
#pragma unroll
            for (int j = 0; j < 4; ++j) pk[j] = f2bf(acc[i][j] + bias);
            *(uint2*)&Vbf[(size_t)m * NV + n0 + tx * 4] = *(uint2*)pk;
        }
    } else {
        unsigned short* dst = (which == 0) ? Qbf : Kbf;
        const int h = (m0 + ty * 4) >> 5;
        const int c0 = (ty * 4) & 31;
        float v[4][4];
#pragma unroll
        for (int i = 0; i < 4; ++i) {
            const int m = m0 + ty * 4 + i;
            const float bias = B[m];
            const int d = m & (HD - 1);
            const float invf =
                __powf(10000.0f, -(float)(d & 15) * (1.0f / 16.0f));
#pragma unroll
            for (int j = 0; j < 4; ++j) {
                const int n = n0 + tx * 4 + j;
                float pos = (float)n * (2.0f / 4095.0f) - 1.0f;
                float ang = pos * invf;
                v[i][j] = (acc[i][j] + bias) * ((d < 16) ? __sinf(ang) : __cosf(ang));
            }
        }
#pragma unroll
        for (int j = 0; j < 4; ++j) {
            const int n = n0 + tx * 4 + j;
            unsigned short pk[4];
#pragma unroll
            for (int i = 0; i < 4; ++i) pk[i] = f2bf(v[i][j]);
            *(uint2*)&dst[((size_t)h * NV + n) * HD + c0] = *(uint2*)pk;
        }
    }
}

// ---------------------------------------------------------------------------
// Kernel 2: flash-style attention, bf16 MFMA, SPLIT-K (additive partials:
// no max-tracking -> unnormalized O and l just add across splits).
// grid (NV/64, NHEAD, NSPLIT), block 256 (4 waves); each block covers
// KSPAN keys. Wave-private P strips in LDS, no __syncthreads in k-loop.
// P uses truncating bf16; lpart accumulates the SAME truncated value so
// numerator/denominator weights match exactly.
// ---------------------------------------------------------------------------
__global__ __launch_bounds__(256) void attn_mfma(
    const unsigned short* __restrict__ Qbf,
    const unsigned short* __restrict__ Kbf,
    const unsigned short* __restrict__ Vbf,
    float* __restrict__ Opart, float* __restrict__ Lpart)
{
    const int h = blockIdx.y;
    const int q0 = blockIdx.x * 64;
    const int z = blockIdx.z;
    const int kbase = z * KSPAN;
    const int t = threadIdx.x;
    const int w = t >> 6;
    const int lane = t & 63;
    const int ln = lane & 15;
    const int quad = lane >> 4;

    __shared__ __align__(16) unsigned short Ps[64][72];  // wave-private strips

    const short8 qa = *(const short8*)
        &Qbf[((size_t)h * NV + q0 + w * 16 + ln) * HD + quad * 8];

    const unsigned short* Kh = Kbf + (size_t)h * NV * HD;
    const unsigned short* Vh = Vbf + (size_t)h * HD * NV;

    f32x4 oacc[2] = {};
    float lpart[4] = {};

    short8 kf[4];
#pragma unroll
    for (int ct = 0; ct < 4; ++ct)
        kf[ct] = *(const short8*)
            &Kh[(size_t)(kbase + ct * 16 + ln) * HD + quad * 8];

    for (int kk = 0; kk < KSPAN; kk += 64) {
        const int kb = kbase + kk;
        const int kbn = kbase + ((kk + 64) & (KSPAN - 1));

        short8 vb[4];
#pragma unroll
        for (int half = 0; half < 2; ++half)
#pragma unroll
            for (int ctile = 0; ctile < 2; ++ctile)
                vb[half * 2 + ctile] = *(const short8*)
                    &Vh[(size_t)(ctile * 16 + ln) * NV + kb + half * 32 + quad * 8];

        f32x4 s[4];
#pragma unroll
        for (int ct = 0; ct < 4; ++ct) {
            f32x4 z4 = {0.f, 0.f, 0.f, 0.f};
            s[ct] = __builtin_amdgcn_mfma_f32_16x16x32_bf16(qa, kf[ct], z4, 0, 0, 0);
        }

        short8 kfn[4];
#pragma unroll
        for (int ct = 0; ct < 4; ++ct)
            kfn[ct] = *(const short8*)
                &Kh[(size_t)(kbn + ct * 16 + ln) * HD + quad * 8];

#pragma unroll
        for (int ct = 0; ct < 4; ++ct) {
#pragma unroll
            for (int r = 0; r < 4; ++r) {
                float p = __expf(s[ct][r]);
                unsigned u = __float_as_uint(p);
                lpart[r] += __uint_as_float(u & 0xffff0000u);  // == bf16(p)
                Ps[w * 16 + quad * 4 + r][ct * 16 + ln] =
                    (unsigned short)(u >> 16);
            }
        }
        __builtin_amdgcn_wave_barrier();

#pragma unroll
        for (int half = 0; half < 2; ++half) {
            const short8 pa =
                *(const short8*)&Ps[w * 16 + ln][half * 32 + quad * 8];
#pragma unroll
            for (int ctile = 0; ctile < 2; ++ctile) {
                oacc[ctile] = __builtin_amdgcn_mfma_f32_16x16x32_bf16(
                    pa, vb[half * 2 + ctile], oacc[ctile], 0, 0, 0);
            }
        }
        __builtin_amdgcn_wave_barrier();

#pragma unroll
        for (int ct = 0; ct < 4; ++ct) kf[ct] = kfn[ct];
    }

    // row sums via width-16 butterfly; all ln lanes end with the sum
    float lsum[4];
#pragma unroll
    for (int r = 0; r < 4; ++r) {
        float v = lpart[r];
        v += __shfl_xor(v, 1, 16);
        v += __shfl_xor(v, 2, 16);
        v += __shfl_xor(v, 4, 16);
        v += __shfl_xor(v, 8, 16);
        lsum[r] = v;
    }

    float* Oz = Opart + (size_t)z * CIN * NV;
    float* Lz = Lpart + (size_t)z * NHEAD * NV;

    if (ln == 0) {
#pragma unroll
        for (int r = 0; r < 4; ++r)
            Lz[(size_t)h * NV + q0 + w * 16 + quad * 4 + r] = lsum[r];
    }

#pragma unroll
    for (int ctile = 0; ctile < 2; ++ctile) {
#pragma unroll
        for (int r = 0; r < 4; ++r) {
            const int q = q0 + w * 16 + quad * 4 + r;
            Oz[(size_t)(h * HD + ctile * 16 + ln) * NV + q] = oacc[ctile][r];
        }
    }
}

// ---------------------------------------------------------------------------
// Kernel 3: combine split-K partials + output projection:
//   A = (O0+O1) / (l0+l1);  out = wo @ (A + qf) + bo
// ---------------------------------------------------------------------------
__global__ __launch_bounds__(256) void out_proj(
    const float* __restrict__ x,
    const float* __restrict__ Opart, const float* __restrict__ Lpart,
    const float* __restrict__ wo, const float* __restrict__ bo,
    float* __restrict__ out)
{
    const int n0 = blockIdx.x * 64;
    const int m0 = blockIdx.y * 64;
    const int t = threadIdx.x;
    const int tx = t & 15, ty = t >> 4;

    const float* O0 = Opart;
    const float* O1 = Opart + (size_t)CIN * NV;
    const float* L0 = Lpart;
    const float* L1 = Lpart + (size_t)NHEAD * NV;

    __shared__ float Wts[16][64];
    __shared__ float Xs[16][64];

    float acc[4][4] = {};

    for (int k0 = 0; k0 < CIN; k0 += 16) {
        {
            int row = t >> 2, c4 = (t & 3) * 4;
            float4 w4 = *(const float4*)&wo[(size_t)(m0 + row) * CIN + k0 + c4];
            Wts[c4 + 0][row] = w4.x;
            Wts[c4 + 1][row] = w4.y;
            Wts[c4 + 2][row] = w4.z;
            Wts[c4 + 3][row] = w4.w;
        }
        {
            int xr = t >> 4, xc = (t & 15) * 4;
            const int ch = k0 + xr;
            const int hh = ch >> 5;
            size_t off = (size_t)ch * NV + n0 + xc;
            size_t loff = (size_t)hh * NV + n0 + xc;
            float4 o0 = *(const float4*)&O0[off];
            float4 o1 = *(const float4*)&O1[off];
            float4 l0 = *(const float4*)&L0[loff];
            float4 l1 = *(const float4*)&L1[loff];
            float4 q4 = *(const float4*)&x[off];
            float4 s4;
            s4.x = (o0.x + o1.x) * __builtin_amdgcn_rcpf(l0.x + l1.x) + q4.x;
            s4.y = (o0.y + o1.y) * __builtin_amdgcn_rcpf(l0.y + l1.y) + q4.y;
            s4.z = (o0.z + o1.z) * __builtin_amdgcn_rcpf(l0.z + l1.z) + q4.z;
            s4.w = (o0.w + o1.w) * __builtin_amdgcn_rcpf(l0.w + l1.w) + q4.w;
            *(float4*)&Xs[xr][xc] = s4;
        }
        __syncthreads();
#pragma unroll
        for (int kk = 0; kk < 16; ++kk) {
            float a[4], b[4];
            *(float4*)a = *(const float4*)&Wts[kk][ty * 4];
            *(float4*)b = *(const float4*)&Xs[kk][tx * 4];
#pragma unroll
            for (int i = 0; i < 4; ++i)
#pragma unroll
                for (int j = 0; j < 4; ++j) acc[i][j] += a[i] * b[j];
        }
        __syncthreads();
    }

#pragma unroll
    for (int i = 0; i < 4; ++i) {
        const int m = m0 + ty * 4 + i;
        const float bias = bo[m];
#pragma unroll
        for (int j = 0; j < 4; ++j) {
            out[(size_t)m * NV + n0 + tx * 4 + j] = acc[i][j] + bias;
        }
    }
}

// ---------------------------------------------------------------------------
extern "C" void kernel_launch(void* const* d_in, const int* in_sizes, int n_in,
                              void* d_out, int out_size, void* d_ws,
                              size_t ws_size, hipStream_t stream)
{
    const float* x  = (const float*)d_in[0];
    const float* wq = (const float*)d_in[1];
    const float* bq = (const float*)d_in[2];
    const float* wk = (const float*)d_in[3];
    const float* bk = (const float*)d_in[4];
    const float* wv = (const float*)d_in[5];
    const float* bv = (const float*)d_in[6];
    const float* wo = (const float*)d_in[7];
    const float* bo = (const float*)d_in[8];
    float* out = (float*)d_out;

    unsigned short* Qbf = (unsigned short*)d_ws;        // 2MB
    unsigned short* Kbf = Qbf + (size_t)CIN * NV;       // 2MB
    unsigned short* Vbf = Kbf + (size_t)CIN * NV;       // 2MB
    float* Opart = (float*)(Vbf + (size_t)CIN * NV);    // NSPLIT * 4MB
    float* Lpart = Opart + (size_t)NSPLIT * CIN * NV;   // NSPLIT * 128KB

    qkv_proj<<<dim3(NV / 64, CIN / 64, 3), 256, 0, stream>>>(
        x, wq, bq, wk, bk, wv, bv, Qbf, Kbf, Vbf);
    attn_mfma<<<dim3(NV / 64, NHEAD, NSPLIT), 256, 0, stream>>>(
        Qbf, Kbf, Vbf, Opart, Lpart);
    out_proj<<<dim3(NV / 64, 512 / 64), 256, 0, stream>>>(
        x, Opart, Lpart, wo, bo, out);
}